// Round 8
// baseline (261.799 us; speedup 1.0000x reference)
//
#include <hip/hip_runtime.h>

#define CHW 262144   // C*H*W = 256*32*32
#define HWD 1024     // H*W

typedef _Float16 v8h __attribute__((ext_vector_type(8)));
typedef _Float16 v4h __attribute__((ext_vector_type(4)));
typedef float    v4f __attribute__((ext_vector_type(4)));

// ws layout (float offsets), total 4243464 floats = 17.0 MB (ws >= 21.1 MB proven r1)
static const unsigned OFF_ASQ  = 0;        // ||z_n||^2 [8192]
static const unsigned OFF_BSQ  = 8192;     // ||e_k||^2 [8192]
static const unsigned OFF_CNT  = 16384;    // counts (int, zeroed by k_prep) [8192]
static const unsigned OFF_HEAD = 24576;    // list heads, n+1, 0=end (int, zeroed) [8192]
static const unsigned OFF_NXT  = 32768;    // list next (int; zeroed harmlessly) [8192]
static const unsigned OFF_FIN  = 40960;    // per-n min key (u32, init 0xFFFFFFFF) [8192]
static const unsigned OFF_SCAL = 49152;    // [0]=loss_sum [1]=sum(cs) (zeroed) [8]
static const unsigned OFF_AH   = 49160;    // Ah fp16 [8192*256] (1048576 floats, 16B-aligned)
static const unsigned OFF_AM   = 1097736;  // Am fp16
static const unsigned OFF_BH   = 2146312;  // Bh fp16
static const unsigned OFF_BM   = 3194888;  // Bm fp16

#define GLL(g, l) __builtin_amdgcn_global_load_lds( \
    (const __attribute__((address_space(1))) void*)(g), \
    (__attribute__((address_space(3))) void*)(l), 16, 0, 0)

// ---- stage 1: ||z||^2 | emb->bsq+fp16 split | z transpose+split | init cnt/head/fin/scal ----
__global__ __launch_bounds__(256) void k_prep(const float* __restrict__ z,
        const float* __restrict__ emb, float* __restrict__ asq, float* __restrict__ bsq,
        _Float16* __restrict__ Bh, _Float16* __restrict__ Bm,
        _Float16* __restrict__ Ah, _Float16* __restrict__ Am,
        float* __restrict__ zerobase) {
    int bx = blockIdx.x;
    int t = threadIdx.x;
    if (bx < 32) {
        // ||z_n||^2 — EXACT sequential 256-chain (bits feed the argmin; do not reorder)
        int n = bx * 256 + t;
        const float* p = z + (size_t)(n >> 10) * CHW + (n & 1023);
        float s = 0.f;
        #pragma unroll 8
        for (int c = 0; c < 256; ++c) { float v = p[(size_t)c << 10]; s = fmaf(v, v, s); }
        asq[n] = s;
    } else if (bx < 2080) {
        int w = (bx - 32) * 4 + (t >> 6);
        int lane = t & 63;
        float4 v = *(const float4*)(emb + (size_t)w * 256 + lane * 4);
        float s = v.x * v.x;
        s = fmaf(v.y, v.y, s); s = fmaf(v.z, v.z, s); s = fmaf(v.w, v.w, s);
        #pragma unroll
        for (int m = 1; m < 64; m <<= 1) s += __shfl_xor(s, m, 64);
        if (lane == 0) bsq[w] = s;
        float e0 = v.x * 8192.0f, e1 = v.y * 8192.0f, e2 = v.z * 8192.0f, e3 = v.w * 8192.0f;
        _Float16 h0 = (_Float16)e0, h1 = (_Float16)e1, h2 = (_Float16)e2, h3 = (_Float16)e3;
        v4h hv = {h0, h1, h2, h3};
        v4h mv = {(_Float16)((e0 - (float)h0) * 2048.0f),
                  (_Float16)((e1 - (float)h1) * 2048.0f),
                  (_Float16)((e2 - (float)h2) * 2048.0f),
                  (_Float16)((e3 - (float)h3) * 2048.0f)};
        *(v4h*)(Bh + (size_t)w * 256 + lane * 4) = hv;
        *(v4h*)(Bm + (size_t)w * 256 + lane * 4) = mv;
    } else if (bx < 2592) {
        __shared__ float s[64][65];
        int blk = bx - 2080;
        int hw0 = (blk & 15) * 64;
        int c0  = ((blk >> 4) & 3) * 64;
        int b   = blk >> 6;
        #pragma unroll
        for (int ii = 0; ii < 16; ++ii) {
            int e = t + ii * 256;
            int c = e >> 6, x = e & 63;
            s[c][x] = z[(size_t)b * CHW + (size_t)(c0 + c) * HWD + hw0 + x];
        }
        __syncthreads();
        int n = t & 63, cseg = (t >> 6) * 16;
        _Float16 hbuf[16], mbuf[16];
        #pragma unroll
        for (int j = 0; j < 16; ++j) {
            float v = s[cseg + j][n];
            _Float16 h = (_Float16)v;
            float r = v - (float)h;
            hbuf[j] = h;
            mbuf[j] = (_Float16)(r * 2048.0f);
        }
        size_t off = ((size_t)b * 1024 + hw0 + n) * 256 + c0 + cseg;
        *(v8h*)(Ah + off)     = *(v8h*)(hbuf);
        *(v8h*)(Ah + off + 8) = *(v8h*)(hbuf + 8);
        *(v8h*)(Am + off)     = *(v8h*)(mbuf);
        *(v8h*)(Am + off + 8) = *(v8h*)(mbuf + 8);
    } else {
        // init: zero cnt[8192]+head[8192]+nxt[8192], fill fin[8192]=0xFFFFFFFF, zero scal
        int idx = (bx - 2592) * 1024 + t * 4;   // 32 blocks cover 32768 u32
        unsigned v = (idx >= 24576) ? 0xFFFFFFFFu : 0u;
        uint4 val = {v, v, v, v};
        *(uint4*)((unsigned*)zerobase + idx) = val;
        if (bx == 2623 && t == 0) {
            *(float4*)(zerobase + 32768) = (float4){0.f, 0.f, 0.f, 0.f};
            *(float4*)(zerobase + 32772) = (float4){0.f, 0.f, 0.f, 0.f};
        }
    }
}

// ---- main: 128x128 tile, 512 threads (8 waves of 32x64), dbuf LDS, 3-product fp16x2 ----
// FROZEN numerics/schedule since r6 (per-element MFMA chains + fl-epilogue bit-identical).
// Epilogue now reduces via atomicMin(fin[n]) — same keys, min is order-invariant.
__global__ __launch_bounds__(512, 4) void k_main(
        const _Float16* __restrict__ Ah, const _Float16* __restrict__ Am,
        const _Float16* __restrict__ Bh, const _Float16* __restrict__ Bm,
        const float* __restrict__ asq, const float* __restrict__ bsq,
        unsigned* __restrict__ fin) {
    __shared__ _Float16 lds[32768];  // 64 KB: 2 buf x (4 mats x [128 rows x 32 halves]), XOR-swizzled
    const int kt = blockIdx.x, nt = blockIdx.y;
    const int n0 = nt * 128, k0 = kt * 128;
    const int t = threadIdx.x;
    const int lane = t & 63, w = t >> 6;       // w in [0,8)
    const int wrow = w >> 1, wcol = w & 1;     // wave tile: rows wrow*32, cols wcol*64
    const int lm = lane & 15, quad = lane >> 4;

    v4f acc1[2][4], acc2[2][4];
    #pragma unroll
    for (int i = 0; i < 2; ++i)
        #pragma unroll
        for (int j = 0; j < 4; ++j) { acc1[i][j] = (v4f){0.f,0.f,0.f,0.f}; acc2[i][j] = (v4f){0.f,0.f,0.f,0.f}; }

    const int row0 = t >> 2;                   // [0,128)
    const int c40 = (t & 3) ^ ((row0 >> 1) & 3);
    const char* gA  = (const char*)Ah + (size_t)(n0 + row0) * 512 + c40 * 16;
    const char* gAm = (const char*)Am + (size_t)(n0 + row0) * 512 + c40 * 16;
    const char* gB  = (const char*)Bh + (size_t)(k0 + row0) * 512 + c40 * 16;
    const char* gBm = (const char*)Bm + (size_t)(k0 + row0) * 512 + c40 * 16;

    int sa[2], sb[4];
    #pragma unroll
    for (int i = 0; i < 2; ++i) {
        int mr = wrow * 32 + i * 16 + lm;
        sa[i] = mr * 32 + ((quad ^ ((mr >> 1) & 3)) * 8);
    }
    #pragma unroll
    for (int j = 0; j < 4; ++j) {
        int nr = wcol * 64 + j * 16 + lm;
        sb[j] = nr * 32 + ((quad ^ ((nr >> 1) & 3)) * 8);
    }

    auto stage = [&](int cb, int buf) {
        const size_t co = (size_t)cb * 64;      // 32 halves per cb
        _Float16* l = lds + buf * 16384 + t * 8;  // lane-linear 16B dest per wave
        GLL(gA + co,  l);
        GLL(gAm + co, l + 4096);
        GLL(gB + co,  l + 8192);
        GLL(gBm + co, l + 12288);
    };

    stage(0, 0);
    for (int cb = 0; cb < 8; ++cb) {
        __syncthreads();
        if (cb < 7) stage(cb + 1, (cb + 1) & 1);
        const _Float16* L = lds + (cb & 1) * 16384;

        v8h fa[2], fam[2];
        #pragma unroll
        for (int i = 0; i < 2; ++i) {
            fa[i]  = *(const v8h*)(L + sa[i]);
            fam[i] = *(const v8h*)(L + 4096 + sa[i]);
        }
        #pragma unroll
        for (int jh = 0; jh < 2; ++jh) {       // j in halves to cap frag registers
            v8h fb0  = *(const v8h*)(L + 8192 + sb[jh * 2]);
            v8h fb1  = *(const v8h*)(L + 8192 + sb[jh * 2 + 1]);
            v8h fbm0 = *(const v8h*)(L + 12288 + sb[jh * 2]);
            v8h fbm1 = *(const v8h*)(L + 12288 + sb[jh * 2 + 1]);
            #pragma unroll
            for (int i = 0; i < 2; ++i) {
                int j0 = jh * 2;
                acc1[i][j0]     = __builtin_amdgcn_mfma_f32_16x16x32_f16(fa[i],  fb0,  acc1[i][j0], 0, 0, 0);
                acc2[i][j0]     = __builtin_amdgcn_mfma_f32_16x16x32_f16(fa[i],  fbm0, acc2[i][j0], 0, 0, 0);
                acc2[i][j0]     = __builtin_amdgcn_mfma_f32_16x16x32_f16(fam[i], fb0,  acc2[i][j0], 0, 0, 0);
                acc1[i][j0 + 1] = __builtin_amdgcn_mfma_f32_16x16x32_f16(fa[i],  fb1,  acc1[i][j0 + 1], 0, 0, 0);
                acc2[i][j0 + 1] = __builtin_amdgcn_mfma_f32_16x16x32_f16(fa[i],  fbm1, acc2[i][j0 + 1], 0, 0, 0);
                acc2[i][j0 + 1] = __builtin_amdgcn_mfma_f32_16x16x32_f16(fam[i], fb1,  acc2[i][j0 + 1], 0, 0, 0);
            }
        }
    }

    // epilogue: d = fl(fl(a+b) - 2*S); u32 key = ((d - a)*2^16 + 32768)<<13 | k  (exact ints)
    float bvv[4];
    #pragma unroll
    for (int j = 0; j < 4; ++j) bvv[j] = bsq[k0 + wcol * 64 + j * 16 + lm];
    #pragma unroll
    for (int i = 0; i < 2; ++i) {
        #pragma unroll
        for (int r = 0; r < 4; ++r) {
            int mm = wrow * 32 + i * 16 + quad * 4 + r;
            float av_ = asq[n0 + mm];
            unsigned best = 0xFFFFFFFFu;
            #pragma unroll
            for (int j = 0; j < 4; ++j) {
                float S = fmaf(acc2[i][j][r], 4.8828125e-4f, acc1[i][j][r]) * 1.220703125e-4f;
                float dd = (av_ + bvv[j]) - 2.0f * S;      // SAME BITS as rounds 3/5/6/7
                float gv = dd - av_;                        // exact (Sterbenz)
                int mi = (int)(gv * 65536.0f) + 32768;      // exact integer
                int col = k0 + wcol * 64 + j * 16 + lm;
                unsigned key = ((unsigned)mi << 13) | (unsigned)col;
                best = key < best ? key : best;
            }
            #pragma unroll
            for (int xm = 1; xm < 16; xm <<= 1) {           // reduce over lm within each quad
                unsigned o = __shfl_xor(best, xm, 64);
                best = o < best ? o : best;
            }
            if (lm == 0) atomicMin(fin + n0 + mm, best);
        }
    }
}

// ---- fused: idx from fin | lists/histogram/cs-sum (y==0) | z_q + loss ----
__global__ __launch_bounds__(256) void k_zqr(const unsigned* __restrict__ fin,
        const float* __restrict__ z, const float* __restrict__ emb, const float* __restrict__ cs,
        float* __restrict__ out_idx, int* __restrict__ cnt,
        int* __restrict__ head, int* __restrict__ nxt,
        float* __restrict__ out_zq, float* __restrict__ scal) {
    const int bx = blockIdx.x, by = blockIdx.y;
    const int n0 = bx * 64, c00 = by * 64;
    const int lane = threadIdx.x & 63, g = threadIdx.x >> 6;
    const int n = n0 + lane;
    const int idxn = (int)(fin[n] & 8191u);

    if (by == 0) {
        if (g == 0) {
            out_idx[n] = (float)idxn;
            atomicAdd(cnt + idxn, 1);
            int old = atomicExch(head + idxn, n + 1);   // 0 = end-of-list
            nxt[n] = old;
        } else if (g == 1) {
            float cv = cs[n];
            #pragma unroll
            for (int m = 1; m < 64; m <<= 1) cv += __shfl_xor(cv, m, 64);
            if (lane == 0) atomicAdd(scal + 1, cv);
        }
    }

    // z_q gather + straight-through write + loss
    int b = n >> 10, hw = n & 1023;
    const float* zr = z + (size_t)b * CHW + hw;
    const float* er = emb + (size_t)idxn * 256;
    float* oz = out_zq + (size_t)b * CHW + hw;
    float ls = 0.f;
    #pragma unroll
    for (int q = 0; q < 4; ++q) {
        int c = c00 + g * 16 + q * 4;
        float4 e4 = *(const float4*)(er + c);
        float ev[4] = {e4.x, e4.y, e4.z, e4.w};
        #pragma unroll
        for (int r = 0; r < 4; ++r) {
            float zp = zr[(size_t)(c + r) << 10];
            float dif = ev[r] - zp;
            oz[(size_t)(c + r) << 10] = zp + dif;
            ls = fmaf(dif, dif, ls);
        }
    }
    #pragma unroll
    for (int m = 1; m < 64; m <<= 1) ls += __shfl_xor(ls, m, 64);
    __shared__ float red[4];
    if (lane == 0) red[g] = ls;
    __syncthreads();
    if (threadIdx.x == 0) atomicAdd(scal, red[0] + red[1] + red[2] + red[3]);
}

// ---- finalize: list-walk dw (zf reconstructed from Ah/Am), new_cs, ema, embedding, loss ----
__global__ __launch_bounds__(256) void k_fin(const float* __restrict__ cs, const float* __restrict__ ema,
        const int* __restrict__ head, const int* __restrict__ nxt,
        const _Float16* __restrict__ Ah, const _Float16* __restrict__ Am,
        const float* __restrict__ scal, const int* __restrict__ cnt,
        float* __restrict__ out_ncs, float* __restrict__ out_ema,
        float* __restrict__ out_emb, float* __restrict__ out_loss) {
    int k = blockIdx.x * 4 + (threadIdx.x >> 6);
    int lane = threadIdx.x & 63;
    // dw[k][:] = sum over assigned n of zf[n][:], zf ~= h + m/2048 (err ~1e-6 << tol)
    float4 dwv = {0.f, 0.f, 0.f, 0.f};
    int cur = head[k];
    while (cur) {
        int n = cur - 1;
        v4h hh = *(const v4h*)(Ah + (size_t)n * 256 + lane * 4);
        v4h mm = *(const v4h*)(Am + (size_t)n * 256 + lane * 4);
        dwv.x += fmaf((float)mm[0], 4.8828125e-4f, (float)hh[0]);
        dwv.y += fmaf((float)mm[1], 4.8828125e-4f, (float)hh[1]);
        dwv.z += fmaf((float)mm[2], 4.8828125e-4f, (float)hh[2]);
        dwv.w += fmaf((float)mm[3], 4.8828125e-4f, (float)hh[3]);
        cur = nxt[n];
    }
    const float C1 = (float)(1.0 - 0.99);
    const float KEPS = (float)(8192 * 1e-5);
    float ncs0v = cs[k] * 0.99f + C1 * (float)cnt[k];
    float nsum = 0.99f * scal[1] + C1 * 8192.0f;   // sum(counts) == N == 8192
    float ncs = (ncs0v + 1e-5f) / (nsum + KEPS) * nsum;
    if (lane == 0) out_ncs[k] = ncs;
    size_t base = (size_t)k * 256 + lane * 4;
    float4 e4 = *(const float4*)(ema + base);
    float r0 = e4.x * 0.99f + C1 * dwv.x;
    float r1 = e4.y * 0.99f + C1 * dwv.y;
    float r2 = e4.z * 0.99f + C1 * dwv.z;
    float r3 = e4.w * 0.99f + C1 * dwv.w;
    out_ema[base + 0] = r0; out_ema[base + 1] = r1; out_ema[base + 2] = r2; out_ema[base + 3] = r3;
    out_emb[base + 0] = r0 / ncs; out_emb[base + 1] = r1 / ncs;
    out_emb[base + 2] = r2 / ncs; out_emb[base + 3] = r3 / ncs;
    if (blockIdx.x == 0 && threadIdx.x == 0) {
        float m = scal[0] * (1.0f / 2097152.0f);
        out_loss[0] = m + 0.25f * m;
    }
}

extern "C" void kernel_launch(void* const* d_in, const int* in_sizes, int n_in,
                              void* d_out, int out_size, void* d_ws, size_t ws_size,
                              hipStream_t stream) {
    const float* z   = (const float*)d_in[0];
    const float* emb = (const float*)d_in[1];
    const float* cs  = (const float*)d_in[2];
    const float* ema = (const float*)d_in[3];
    float* out = (float*)d_out;
    float* wsf = (float*)d_ws;

    float* asq  = wsf + OFF_ASQ;
    float* bsq  = wsf + OFF_BSQ;
    int*   cnt  = (int*)(wsf + OFF_CNT);
    int*   head = (int*)(wsf + OFF_HEAD);
    int*   nxt  = (int*)(wsf + OFF_NXT);
    unsigned* fin = (unsigned*)(wsf + OFF_FIN);
    float* scal = wsf + OFF_SCAL;
    _Float16* Ah = (_Float16*)(wsf + OFF_AH);
    _Float16* Am = (_Float16*)(wsf + OFF_AM);
    _Float16* Bh = (_Float16*)(wsf + OFF_BH);
    _Float16* Bm = (_Float16*)(wsf + OFF_BM);

    float* out_zq   = out;                 // [2097152]
    float* out_loss = out + 2097152;       // [1]
    float* out_idx  = out + 2097153;       // [8192]
    float* out_ncs  = out + 2105345;       // [8192]
    float* out_ema  = out + 2113537;       // [2097152]
    float* out_emb  = out + 4210689;       // [2097152]

    k_prep<<<2624, 256, 0, stream>>>(z, emb, asq, bsq, Bh, Bm, Ah, Am, wsf + OFF_CNT);
    k_main<<<dim3(64, 64), 512, 0, stream>>>(Ah, Am, Bh, Bm, asq, bsq, fin);
    k_zqr<<<dim3(128, 4), 256, 0, stream>>>(fin, z, emb, cs, out_idx, cnt, head, nxt, out_zq, scal);
    k_fin<<<2048, 256, 0, stream>>>(cs, ema, head, nxt, Ah, Am, scal, cnt, out_ncs, out_ema, out_emb, out_loss);
}

// Round 9
// 241.468 us; speedup vs baseline: 1.0842x; 1.0842x over previous
//
#include <hip/hip_runtime.h>

#define CHW 262144   // C*H*W = 256*32*32
#define HWD 1024     // H*W

typedef _Float16 v8h __attribute__((ext_vector_type(8)));
typedef _Float16 v4h __attribute__((ext_vector_type(4)));
typedef float    v4f __attribute__((ext_vector_type(4)));

// ws layout (float offsets), total 4235272 floats = 16.9 MB
static const unsigned OFF_ASQ  = 0;        // ||z_n||^2 [8192]
static const unsigned OFF_BSQ  = 8192;     // ||e_k||^2 [8192]
static const unsigned OFF_CNT  = 16384;    // counts (int, zeroed by k_prep) [8192]
static const unsigned OFF_HEAD = 24576;    // list heads, n+1, 0=end (int, zeroed) [8192]
static const unsigned OFF_NXT  = 32768;    // list next (int; fully written) [8192]
static const unsigned OFF_SCAL = 40960;    // [0]=loss_sum [1]=sum(cs) (zeroed) [8]
static const unsigned OFF_AH   = 40968;    // Ah fp16 [8192*256] (1048576 floats, 16B-aligned)
static const unsigned OFF_AM   = 1089544;  // Am fp16
static const unsigned OFF_BH   = 2138120;  // Bh fp16
static const unsigned OFF_BM   = 3186696;  // Bm fp16
// pdk u32[8192][128] (4 MB) lives in d_out's out_ema region (dead until k_fin writes it)

#define GLL(g, l) __builtin_amdgcn_global_load_lds( \
    (const __attribute__((address_space(1))) void*)(g), \
    (__attribute__((address_space(3))) void*)(l), 16, 0, 0)

// ---- stage 1: ||z||^2 | emb->bsq+fp16 split | z transpose+split | zero cnt/head/scal ----
__global__ __launch_bounds__(256) void k_prep(const float* __restrict__ z,
        const float* __restrict__ emb, float* __restrict__ asq, float* __restrict__ bsq,
        _Float16* __restrict__ Bh, _Float16* __restrict__ Bm,
        _Float16* __restrict__ Ah, _Float16* __restrict__ Am,
        float* __restrict__ zerobase) {
    int bx = blockIdx.x;
    int t = threadIdx.x;
    if (bx < 32) {
        // ||z_n||^2 — EXACT sequential 256-chain (bits feed the argmin; do not reorder)
        int n = bx * 256 + t;
        const float* p = z + (size_t)(n >> 10) * CHW + (n & 1023);
        float s = 0.f;
        #pragma unroll 8
        for (int c = 0; c < 256; ++c) { float v = p[(size_t)c << 10]; s = fmaf(v, v, s); }
        asq[n] = s;
    } else if (bx < 2080) {
        int w = (bx - 32) * 4 + (t >> 6);
        int lane = t & 63;
        float4 v = *(const float4*)(emb + (size_t)w * 256 + lane * 4);
        float s = v.x * v.x;
        s = fmaf(v.y, v.y, s); s = fmaf(v.z, v.z, s); s = fmaf(v.w, v.w, s);
        #pragma unroll
        for (int m = 1; m < 64; m <<= 1) s += __shfl_xor(s, m, 64);
        if (lane == 0) bsq[w] = s;
        float e0 = v.x * 8192.0f, e1 = v.y * 8192.0f, e2 = v.z * 8192.0f, e3 = v.w * 8192.0f;
        _Float16 h0 = (_Float16)e0, h1 = (_Float16)e1, h2 = (_Float16)e2, h3 = (_Float16)e3;
        v4h hv = {h0, h1, h2, h3};
        v4h mv = {(_Float16)((e0 - (float)h0) * 2048.0f),
                  (_Float16)((e1 - (float)h1) * 2048.0f),
                  (_Float16)((e2 - (float)h2) * 2048.0f),
                  (_Float16)((e3 - (float)h3) * 2048.0f)};
        *(v4h*)(Bh + (size_t)w * 256 + lane * 4) = hv;
        *(v4h*)(Bm + (size_t)w * 256 + lane * 4) = mv;
    } else if (bx < 2592) {
        __shared__ float s[64][65];
        int blk = bx - 2080;
        int hw0 = (blk & 15) * 64;
        int c0  = ((blk >> 4) & 3) * 64;
        int b   = blk >> 6;
        #pragma unroll
        for (int ii = 0; ii < 16; ++ii) {
            int e = t + ii * 256;
            int c = e >> 6, x = e & 63;
            s[c][x] = z[(size_t)b * CHW + (size_t)(c0 + c) * HWD + hw0 + x];
        }
        __syncthreads();
        int n = t & 63, cseg = (t >> 6) * 16;
        _Float16 hbuf[16], mbuf[16];
        #pragma unroll
        for (int j = 0; j < 16; ++j) {
            float v = s[cseg + j][n];
            _Float16 h = (_Float16)v;
            float r = v - (float)h;
            hbuf[j] = h;
            mbuf[j] = (_Float16)(r * 2048.0f);
        }
        size_t off = ((size_t)b * 1024 + hw0 + n) * 256 + c0 + cseg;
        *(v8h*)(Ah + off)     = *(v8h*)(hbuf);
        *(v8h*)(Ah + off + 8) = *(v8h*)(hbuf + 8);
        *(v8h*)(Am + off)     = *(v8h*)(mbuf);
        *(v8h*)(Am + off + 8) = *(v8h*)(mbuf + 8);
    } else {
        // zero cnt[8192] + head[8192] + scal
        int idx = (bx - 2592) * 1024 + t * 4;   // 16 blocks cover 16384 u32
        *(float4*)(zerobase + idx) = (float4){0.f, 0.f, 0.f, 0.f};
        if (bx == 2592 && t == 0)
            *(float4*)(zerobase + 24576) = (float4){0.f, 0.f, 0.f, 0.f};   // scal[0..3]
    }
}

// ---- main: 128x128 tile, 512 threads (8 waves of 32x64), dbuf LDS, 3-product fp16x2 ----
// FROZEN numerics/schedule since r6 (per-element MFMA chains + fl-epilogue bit-identical).
// Epilogue: keys assembled in LDS, one dense 1KB coalesced store per block (no RMW amp).
__global__ __launch_bounds__(512, 4) void k_main(
        const _Float16* __restrict__ Ah, const _Float16* __restrict__ Am,
        const _Float16* __restrict__ Bh, const _Float16* __restrict__ Bm,
        const float* __restrict__ asq, const float* __restrict__ bsq,
        unsigned* __restrict__ pdk) {
    __shared__ _Float16 lds[32768];  // 64 KB: 2 buf x (4 mats x [128 rows x 32 halves]), XOR-swizzled
    const int kt = blockIdx.x, nt = blockIdx.y;
    const int n0 = nt * 128, k0 = kt * 128;
    const int t = threadIdx.x;
    const int lane = t & 63, w = t >> 6;       // w in [0,8)
    const int wrow = w >> 1, wcol = w & 1;     // wave tile: rows wrow*32, cols wcol*64
    const int lm = lane & 15, quad = lane >> 4;

    v4f acc1[2][4], acc2[2][4];
    #pragma unroll
    for (int i = 0; i < 2; ++i)
        #pragma unroll
        for (int j = 0; j < 4; ++j) { acc1[i][j] = (v4f){0.f,0.f,0.f,0.f}; acc2[i][j] = (v4f){0.f,0.f,0.f,0.f}; }

    const int row0 = t >> 2;                   // [0,128)
    const int c40 = (t & 3) ^ ((row0 >> 1) & 3);
    const char* gA  = (const char*)Ah + (size_t)(n0 + row0) * 512 + c40 * 16;
    const char* gAm = (const char*)Am + (size_t)(n0 + row0) * 512 + c40 * 16;
    const char* gB  = (const char*)Bh + (size_t)(k0 + row0) * 512 + c40 * 16;
    const char* gBm = (const char*)Bm + (size_t)(k0 + row0) * 512 + c40 * 16;

    int sa[2], sb[4];
    #pragma unroll
    for (int i = 0; i < 2; ++i) {
        int mr = wrow * 32 + i * 16 + lm;
        sa[i] = mr * 32 + ((quad ^ ((mr >> 1) & 3)) * 8);
    }
    #pragma unroll
    for (int j = 0; j < 4; ++j) {
        int nr = wcol * 64 + j * 16 + lm;
        sb[j] = nr * 32 + ((quad ^ ((nr >> 1) & 3)) * 8);
    }

    auto stage = [&](int cb, int buf) {
        const size_t co = (size_t)cb * 64;      // 32 halves per cb
        _Float16* l = lds + buf * 16384 + t * 8;  // lane-linear 16B dest per wave
        GLL(gA + co,  l);
        GLL(gAm + co, l + 4096);
        GLL(gB + co,  l + 8192);
        GLL(gBm + co, l + 12288);
    };

    stage(0, 0);
    for (int cb = 0; cb < 8; ++cb) {
        __syncthreads();
        if (cb < 7) stage(cb + 1, (cb + 1) & 1);
        const _Float16* L = lds + (cb & 1) * 16384;

        v8h fa[2], fam[2];
        #pragma unroll
        for (int i = 0; i < 2; ++i) {
            fa[i]  = *(const v8h*)(L + sa[i]);
            fam[i] = *(const v8h*)(L + 4096 + sa[i]);
        }
        #pragma unroll
        for (int jh = 0; jh < 2; ++jh) {       // j in halves to cap frag registers
            v8h fb0  = *(const v8h*)(L + 8192 + sb[jh * 2]);
            v8h fb1  = *(const v8h*)(L + 8192 + sb[jh * 2 + 1]);
            v8h fbm0 = *(const v8h*)(L + 12288 + sb[jh * 2]);
            v8h fbm1 = *(const v8h*)(L + 12288 + sb[jh * 2 + 1]);
            #pragma unroll
            for (int i = 0; i < 2; ++i) {
                int j0 = jh * 2;
                acc1[i][j0]     = __builtin_amdgcn_mfma_f32_16x16x32_f16(fa[i],  fb0,  acc1[i][j0], 0, 0, 0);
                acc2[i][j0]     = __builtin_amdgcn_mfma_f32_16x16x32_f16(fa[i],  fbm0, acc2[i][j0], 0, 0, 0);
                acc2[i][j0]     = __builtin_amdgcn_mfma_f32_16x16x32_f16(fam[i], fb0,  acc2[i][j0], 0, 0, 0);
                acc1[i][j0 + 1] = __builtin_amdgcn_mfma_f32_16x16x32_f16(fa[i],  fb1,  acc1[i][j0 + 1], 0, 0, 0);
                acc2[i][j0 + 1] = __builtin_amdgcn_mfma_f32_16x16x32_f16(fa[i],  fbm1, acc2[i][j0 + 1], 0, 0, 0);
                acc2[i][j0 + 1] = __builtin_amdgcn_mfma_f32_16x16x32_f16(fam[i], fb1,  acc2[i][j0 + 1], 0, 0, 0);
            }
        }
    }

    // epilogue: d = fl(fl(a+b) - 2*S); u32 key = ((d - a)*2^16 + 32768)<<13 | k  (exact ints)
    float bvv[4];
    #pragma unroll
    for (int j = 0; j < 4; ++j) bvv[j] = bsq[k0 + wcol * 64 + j * 16 + lm];
    __syncthreads();                            // LDS reuse for key assembly
    unsigned* lrow = (unsigned*)lds;            // [256]: wcol*128 + mm
    #pragma unroll
    for (int i = 0; i < 2; ++i) {
        #pragma unroll
        for (int r = 0; r < 4; ++r) {
            int mm = wrow * 32 + i * 16 + quad * 4 + r;
            float av_ = asq[n0 + mm];
            unsigned best = 0xFFFFFFFFu;
            #pragma unroll
            for (int j = 0; j < 4; ++j) {
                float S = fmaf(acc2[i][j][r], 4.8828125e-4f, acc1[i][j][r]) * 1.220703125e-4f;
                float dd = (av_ + bvv[j]) - 2.0f * S;      // SAME BITS as rounds 3/5/6/7/8
                float gv = dd - av_;                        // exact (Sterbenz)
                int mi = (int)(gv * 65536.0f) + 32768;      // exact integer
                int col = k0 + wcol * 64 + j * 16 + lm;
                unsigned key = ((unsigned)mi << 13) | (unsigned)col;
                best = key < best ? key : best;
            }
            #pragma unroll
            for (int xm = 1; xm < 16; xm <<= 1) {           // reduce over lm within each quad
                unsigned o = __shfl_xor(best, xm, 64);
                best = o < best ? o : best;
            }
            if (lm == 0) lrow[wcol * 128 + mm] = best;
        }
    }
    __syncthreads();
    // one dense, coalesced 1 KB store: rows (nt*128 + kt*2 + {0,1})
    if (t < 256) pdk[(((size_t)nt * 128 + kt * 2) << 7) + t] = lrow[t];
}

// ---- fused: per-block key reduce -> idx | lists/histogram/cs-sum (y==0) | z_q + loss ----
__global__ __launch_bounds__(256) void k_zqr(const unsigned* __restrict__ pdk,
        const float* __restrict__ z, const float* __restrict__ emb, const float* __restrict__ cs,
        float* __restrict__ out_idx, int* __restrict__ cnt,
        int* __restrict__ head, int* __restrict__ nxt,
        float* __restrict__ out_zq, float* __restrict__ scal) {
    const int bx = blockIdx.x, by = blockIdx.y;
    const int n0 = bx * 64, c00 = by * 64;
    const int lane = threadIdx.x & 63, g = threadIdx.x >> 6;
    const int nt = bx >> 1, mb = (bx & 1) * 64;

    // phase 1: min over 128 j-rows for the block's 64 n; lane l ends with n0+l's key
    unsigned mn = 0xFFFFFFFFu;
    const unsigned* base = pdk + (((size_t)nt * 128 + g * 32) << 7) + mb + lane;
    #pragma unroll 8
    for (int jj = 0; jj < 32; ++jj) {
        unsigned key = base[jj << 7];          // coalesced 256B run per j
        mn = key < mn ? key : mn;
    }
    __shared__ unsigned part[4][64];
    part[g][lane] = mn;
    __syncthreads();
    unsigned k0v = part[0][lane], k1v = part[1][lane];
    unsigned k2v = part[2][lane], k3v = part[3][lane];
    unsigned f01 = k0v < k1v ? k0v : k1v;
    unsigned f23 = k2v < k3v ? k2v : k3v;
    unsigned fkey = f01 < f23 ? f01 : f23;
    int idxn = (int)(fkey & 8191u);
    int n = n0 + lane;

    if (by == 0) {
        if (g == 0) {
            out_idx[n] = (float)idxn;
            atomicAdd(cnt + idxn, 1);
            int old = atomicExch(head + idxn, n + 1);   // 0 = end-of-list
            nxt[n] = old;
        } else if (g == 1) {
            float cv = cs[n];
            #pragma unroll
            for (int m = 1; m < 64; m <<= 1) cv += __shfl_xor(cv, m, 64);
            if (lane == 0) atomicAdd(scal + 1, cv);
        }
    }

    // phase 2: z_q gather + straight-through write + loss
    int b = n >> 10, hw = n & 1023;
    const float* zr = z + (size_t)b * CHW + hw;
    const float* er = emb + (size_t)idxn * 256;
    float* oz = out_zq + (size_t)b * CHW + hw;
    float ls = 0.f;
    #pragma unroll
    for (int q = 0; q < 4; ++q) {
        int c = c00 + g * 16 + q * 4;
        float4 e4 = *(const float4*)(er + c);
        float ev[4] = {e4.x, e4.y, e4.z, e4.w};
        #pragma unroll
        for (int r = 0; r < 4; ++r) {
            float zp = zr[(size_t)(c + r) << 10];
            float dif = ev[r] - zp;
            oz[(size_t)(c + r) << 10] = zp + dif;
            ls = fmaf(dif, dif, ls);
        }
    }
    #pragma unroll
    for (int m = 1; m < 64; m <<= 1) ls += __shfl_xor(ls, m, 64);
    __shared__ float red[4];
    if (lane == 0) red[g] = ls;
    __syncthreads();
    if (threadIdx.x == 0) atomicAdd(scal, red[0] + red[1] + red[2] + red[3]);
}

// ---- finalize: list-walk dw (zf reconstructed from Ah/Am), new_cs, ema, embedding, loss ----
__global__ __launch_bounds__(256) void k_fin(const float* __restrict__ cs, const float* __restrict__ ema,
        const int* __restrict__ head, const int* __restrict__ nxt,
        const _Float16* __restrict__ Ah, const _Float16* __restrict__ Am,
        const float* __restrict__ scal, const int* __restrict__ cnt,
        float* __restrict__ out_ncs, float* __restrict__ out_ema,
        float* __restrict__ out_emb, float* __restrict__ out_loss) {
    int k = blockIdx.x * 4 + (threadIdx.x >> 6);
    int lane = threadIdx.x & 63;
    // dw[k][:] = sum over assigned n of zf[n][:], zf ~= h + m/2048 (err ~1e-6 << tol)
    float4 dwv = {0.f, 0.f, 0.f, 0.f};
    int cur = head[k];
    while (cur) {
        int n = cur - 1;
        v4h hh = *(const v4h*)(Ah + (size_t)n * 256 + lane * 4);
        v4h mm = *(const v4h*)(Am + (size_t)n * 256 + lane * 4);
        dwv.x += fmaf((float)mm[0], 4.8828125e-4f, (float)hh[0]);
        dwv.y += fmaf((float)mm[1], 4.8828125e-4f, (float)hh[1]);
        dwv.z += fmaf((float)mm[2], 4.8828125e-4f, (float)hh[2]);
        dwv.w += fmaf((float)mm[3], 4.8828125e-4f, (float)hh[3]);
        cur = nxt[n];
    }
    const float C1 = (float)(1.0 - 0.99);
    const float KEPS = (float)(8192 * 1e-5);
    float ncs0v = cs[k] * 0.99f + C1 * (float)cnt[k];
    float nsum = 0.99f * scal[1] + C1 * 8192.0f;   // sum(counts) == N == 8192
    float ncs = (ncs0v + 1e-5f) / (nsum + KEPS) * nsum;
    if (lane == 0) out_ncs[k] = ncs;
    size_t base = (size_t)k * 256 + lane * 4;
    float4 e4 = *(const float4*)(ema + base);
    float r0 = e4.x * 0.99f + C1 * dwv.x;
    float r1 = e4.y * 0.99f + C1 * dwv.y;
    float r2 = e4.z * 0.99f + C1 * dwv.z;
    float r3 = e4.w * 0.99f + C1 * dwv.w;
    out_ema[base + 0] = r0; out_ema[base + 1] = r1; out_ema[base + 2] = r2; out_ema[base + 3] = r3;
    out_emb[base + 0] = r0 / ncs; out_emb[base + 1] = r1 / ncs;
    out_emb[base + 2] = r2 / ncs; out_emb[base + 3] = r3 / ncs;
    if (blockIdx.x == 0 && threadIdx.x == 0) {
        float m = scal[0] * (1.0f / 2097152.0f);
        out_loss[0] = m + 0.25f * m;
    }
}

extern "C" void kernel_launch(void* const* d_in, const int* in_sizes, int n_in,
                              void* d_out, int out_size, void* d_ws, size_t ws_size,
                              hipStream_t stream) {
    const float* z   = (const float*)d_in[0];
    const float* emb = (const float*)d_in[1];
    const float* cs  = (const float*)d_in[2];
    const float* ema = (const float*)d_in[3];
    float* out = (float*)d_out;
    float* wsf = (float*)d_ws;

    float* asq  = wsf + OFF_ASQ;
    float* bsq  = wsf + OFF_BSQ;
    int*   cnt  = (int*)(wsf + OFF_CNT);
    int*   head = (int*)(wsf + OFF_HEAD);
    int*   nxt  = (int*)(wsf + OFF_NXT);
    float* scal = wsf + OFF_SCAL;
    _Float16* Ah = (_Float16*)(wsf + OFF_AH);
    _Float16* Am = (_Float16*)(wsf + OFF_AM);
    _Float16* Bh = (_Float16*)(wsf + OFF_BH);
    _Float16* Bm = (_Float16*)(wsf + OFF_BM);

    float* out_zq   = out;                 // [2097152]
    float* out_loss = out + 2097152;       // [1]
    float* out_idx  = out + 2097153;       // [8192]
    float* out_ncs  = out + 2105345;       // [8192]
    float* out_ema  = out + 2113537;       // [2097152]
    float* out_emb  = out + 4210689;       // [2097152]

    // pdk (4 MB) aliases the dead out_ema region: written by k_main, read by k_zqr,
    // overwritten only later by k_fin's out_ema stores.
    unsigned* pdk = (unsigned*)(out + 2113540);   // 16B-aligned

    k_prep<<<2608, 256, 0, stream>>>(z, emb, asq, bsq, Bh, Bm, Ah, Am, wsf + OFF_CNT);
    k_main<<<dim3(64, 64), 512, 0, stream>>>(Ah, Am, Bh, Bm, asq, bsq, pdk);
    k_zqr<<<dim3(128, 4), 256, 0, stream>>>(pdk, z, emb, cs, out_idx, cnt, head, nxt, out_zq, scal);
    k_fin<<<2048, 256, 0, stream>>>(cs, ema, head, nxt, Ah, Am, scal, cnt, out_ncs, out_ema, out_emb, out_loss);
}